// Round 1
// baseline (230.240 us; speedup 1.0000x reference)
//
#include <hip/hip_runtime.h>

// Shifted-window MSA, fixed shape: B=16, H=W=56, C=256, NH=8, hd=32, WS=7, SS=3.
// Pipeline:
//   convert : weights -> transposed bf16 Wt[n][k]; zpad; biasM[type][h] =
//             (rel-pos bias + shift mask + col-pad mask) in MFMA C-fragment layout
//   qkv_gemm: QKVb[m][768] = roll/window-partition(query) @ w_qkv + b
//             (A fused: fp32 gather + bf16 convert + ds_write; B via gll16;
//              XCD-bijective block swizzle so n-blocks sharing A stay on one L2)
//   attn    : barrier-free; 1 wave = 1 (window, head); coalesced fragment bias
//   proj    : out = O @ w_proj + b; LDS-transposed epilogue, full-line stores
// ws (u16): zpad[128]|Wtq[196608]|Wtp[65536]|biasM[131072]|
//           QKVb[P*2408448]|O[P*802816];  P = images/pass from ws_size.

#define IMG 56
#define SCALE 0.17677669529663687f

typedef unsigned short u16;
typedef unsigned int u32;
typedef unsigned long long u64;
typedef __attribute__((ext_vector_type(8))) short short8;   // 8 bf16
typedef __attribute__((ext_vector_type(4))) float floatx4;  // MFMA C/D

__device__ __forceinline__ float bflo(u32 u) { return __uint_as_float(u << 16); }
__device__ __forceinline__ u16 f2bf(float f) {
  u32 u = __float_as_uint(f);
  return (u16)((u + 0x7fffu + ((u >> 16) & 1u)) >> 16);  // RNE
}
#define MFMA(a, b, c) __builtin_amdgcn_mfma_f32_16x16x32_bf16(a, b, c, 0, 0, 0)

__device__ __forceinline__ void gll16(const void* g, const void* l) {
  __builtin_amdgcn_global_load_lds(
      (const __attribute__((address_space(1))) void*)g,
      (__attribute__((address_space(3))) void*)l, 16, 0, 0);
}
#define FENCE_VM() __asm__ volatile("s_waitcnt vmcnt(0)" ::: "memory")
#define FENCE_LGKM() __asm__ volatile("s_waitcnt lgkmcnt(0)" ::: "memory")

// Bijective XCD swizzle (m204): HW sends block b to XCD b%8; give each XCD a
// contiguous chunk of the logical tile space so A-sharing blocks hit one L2.
__device__ __forceinline__ int xcd_swizzle(int orig, int nwg) {
  int q = nwg >> 3, r = nwg & 7;
  int xcd = orig & 7, loc = orig >> 3;
  return (xcd < r ? xcd * (q + 1) : r * (q + 1) + (xcd - r) * q) + loc;
}

// ---------------- Kernel 0: weights + zpad + fragment-layout bias tables --------
// biasM[type][h][mt][quad][l15][nt][reg] (bf16), type = bndH*2+bndV.
__global__ __launch_bounds__(256) void convert_kernel(
    const float* __restrict__ w_qkv, const float* __restrict__ w_proj,
    const float* __restrict__ bias_table, u16* __restrict__ zpad,
    u16* __restrict__ Wtq, u16* __restrict__ Wtp, u16* __restrict__ biasM) {
  int t = blockIdx.x * 256 + threadIdx.x;
  if (t < 196608) {            // w_qkv[k][n]
    int n = t % 768, k = t / 768;
    Wtq[n * 256 + k] = f2bf(w_qkv[t]);
  } else if (t < 262144) {     // w_proj[k][n]
    int u = t - 196608;
    int n = u & 255, k = u >> 8;
    Wtp[n * 256 + k] = f2bf(w_proj[u]);
  } else if (t < 262272) {
    zpad[t - 262144] = 0;
  } else if (t < 393344) {
    int idx = t - 262272;              // [type:2][h:3][mt:2][quad:2][l15:4][nt:2][reg:2]
    int type = idx >> 15;
    int r = idx & 32767;
    int h = r >> 12, mt = (r >> 10) & 3, quad = (r >> 8) & 3;
    int l15 = (r >> 4) & 15, nt = (r >> 2) & 3, reg = r & 3;
    int row = 16 * mt + 4 * quad + reg;
    int col = 16 * nt + l15;
    float v;
    if (col >= 49) v = -1e30f;
    else if (row >= 49) v = 0.f;
    else {
      int yn = row / 7, xn = row - yn * 7;
      int ym = col / 7, xm = col - ym * 7;
      v = bias_table[((yn - ym + 6) * 13 + (xn - xm + 6)) * 8 + h];
      int bndH = (type >> 1) & 1, bndV = type & 1;
      int rc = (bndH ? ((yn < 4) ? 1 : 2) : 0) * 3 + (bndV ? ((xn < 4) ? 1 : 2) : 0);
      int cc = (bndH ? ((ym < 4) ? 1 : 2) : 0) * 3 + (bndV ? ((xm < 4) ? 1 : 2) : 0);
      if (rc != cc) v -= 100.f;
    }
    biasM[idx] = f2bf(v);
  }
}

// ---------------- Kernel 1: QKV GEMM (M=Mrows, N=768, K=256), fused xconv -------
// A rows come straight from query (fp32) with the roll/window-partition mapping,
// converted to bf16 in registers and ds_written into the swizzled LDS slot.
__global__ __launch_bounds__(256) void qkv_gemm(
    const float* __restrict__ query, const u16* __restrict__ Wtq,
    const float* __restrict__ b_qkv, u16* __restrict__ QKVb,
    int img0, int Mrows, int mtiles) {
  union LU {
    struct { u16 As[128][64]; u16 Bs[128][64]; } s;
    u16 Cs[128][144];
  };
  __shared__ LU L;
  __shared__ float bqs[128];
  const int tid = threadIdx.x;
  const int wgid = xcd_swizzle(blockIdx.x, mtiles * 6);
  const int n0 = (wgid % 6) << 7;   // n-inner: 6 consecutive logical blocks share A
  const int m0 = (wgid / 6) << 7;
  const int lane = tid & 63, w = tid >> 6;
  const int l15 = lane & 15, quad = lane >> 4;
  const int mq = w & 1, nq = w >> 1;
  if (tid < 128) bqs[tid] = b_qkv[n0 + tid];

  // Per-c staging geometry (ki-invariant): row/sub within the 128x64 tile, and
  // the query base pointer for the A row's (rolled, window-partitioned) token.
  int rowc[4], subc[4];
  const float* qsrc[4];
  #pragma unroll
  for (int c = 0; c < 4; ++c) {
    int e = (w * 4 + c) * 64 + lane;         // 0..1023
    int row = e >> 3, sp = e & 7, sub = sp ^ (row & 7);
    rowc[c] = row; subc[c] = sub;
    int gr = m0 + row; if (gr >= Mrows) gr = 0;
    int winl = gr / 49, tok = gr - winl * 49;
    int bL = winl >> 6, wi = (winl >> 3) & 7, wj = winl & 7;
    int pr = tok / 7, pc = tok - pr * 7;
    int y = wi * 7 + pr + 3; if (y >= IMG) y -= IMG;
    int x = wj * 7 + pc + 3; if (x >= IMG) x -= IMG;
    qsrc[c] = query + (((size_t)((img0 + bL) * 3136 + y * IMG + x)) << 8) + sub * 8;
  }

  const floatx4 z4 = {0.f, 0.f, 0.f, 0.f};
  floatx4 acc[4][4];
  #pragma unroll
  for (int i = 0; i < 4; ++i)
    #pragma unroll
    for (int j = 0; j < 4; ++j) acc[i][j] = z4;

  for (int ki = 0; ki < 4; ++ki) {
    const int k0 = ki * 64;
    __syncthreads();
    // A: issue fp32 loads first (stay in flight under the B gll16 issue)
    float4 a0[4], a1[4];
    #pragma unroll
    for (int c = 0; c < 4; ++c) {
      const float* src = qsrc[c] + k0;
      a0[c] = reinterpret_cast<const float4*>(src)[0];
      a1[c] = reinterpret_cast<const float4*>(src)[1];
    }
    #pragma unroll
    for (int c = 0; c < 4; ++c)
      gll16(Wtq + (size_t)(n0 + rowc[c]) * 256 + k0 + subc[c] * 8,
            (const char*)&L.s.Bs[0][0] + (w * 4 + c) * 1024);
    #pragma unroll
    for (int c = 0; c < 4; ++c) {
      short8 pk;
      pk[0] = (short)f2bf(a0[c].x); pk[1] = (short)f2bf(a0[c].y);
      pk[2] = (short)f2bf(a0[c].z); pk[3] = (short)f2bf(a0[c].w);
      pk[4] = (short)f2bf(a1[c].x); pk[5] = (short)f2bf(a1[c].y);
      pk[6] = (short)f2bf(a1[c].z); pk[7] = (short)f2bf(a1[c].w);
      *reinterpret_cast<short8*>(
          (char*)&L.s.As[0][0] + (w * 4 + c) * 1024 + lane * 16) = pk;
    }
    FENCE_VM();
    __syncthreads();   // barrier drains lgkm -> ds_writes visible
    #pragma unroll
    for (int ks = 0; ks < 2; ++ks) {
      short8 af[4], bfv[4];
      #pragma unroll
      for (int mt = 0; mt < 4; ++mt) {
        int r = 64 * mq + 16 * mt + l15;
        af[mt] = *reinterpret_cast<const short8*>(
            &L.s.As[r][((4 * ks + quad) ^ (l15 & 7)) * 8]);
      }
      #pragma unroll
      for (int nt = 0; nt < 4; ++nt) {
        int r = 64 * nq + 16 * nt + l15;
        bfv[nt] = *reinterpret_cast<const short8*>(
            &L.s.Bs[r][((4 * ks + quad) ^ (l15 & 7)) * 8]);
      }
      #pragma unroll
      for (int mt = 0; mt < 4; ++mt)
        #pragma unroll
        for (int nt = 0; nt < 4; ++nt)
          acc[mt][nt] = MFMA(af[mt], bfv[nt], acc[mt][nt]);
    }
  }
  __syncthreads();
  #pragma unroll
  for (int mt = 0; mt < 4; ++mt)
    #pragma unroll
    for (int nt = 0; nt < 4; ++nt) {
      float bias = bqs[64 * nq + 16 * nt + l15];
      #pragma unroll
      for (int reg = 0; reg < 4; ++reg) {
        int row = 64 * mq + 16 * mt + 4 * quad + reg;
        int col = 64 * nq + 16 * nt + l15;
        L.Cs[row][col] = f2bf(acc[mt][nt][reg] + bias);
      }
    }
  __syncthreads();
  int r = tid >> 1, half = tid & 1;
  if (m0 + r < Mrows) {
    u16* dst = QKVb + (size_t)(m0 + r) * 768 + n0 + half * 64;
    const u16* src = &L.Cs[r][half * 64];
    #pragma unroll
    for (int it = 0; it < 8; ++it)
      reinterpret_cast<uint4*>(dst)[it] = reinterpret_cast<const uint4*>(src)[it];
  }
}

// ---------------- Kernel 2: attention — barrier-free, 1 wave = (window, head) ----
__global__ __launch_bounds__(256) void attn_kernel(
    const u16* __restrict__ QKVb, const u16* __restrict__ biasM,
    const u16* __restrict__ zpad, u16* __restrict__ O) {
  __shared__ __align__(16) u16 wbuf[4][6144];  // per-wave: Q[64][32],K[64][32],Vt[32][64]
  const int tid = threadIdx.x;
  const int winl = blockIdx.x >> 1;
  const int hg = (blockIdx.x & 1) * 4;
  const int lane = tid & 63, w = tid >> 6;
  const int l15 = lane & 15, quad = lane >> 4;
  const int h = hg + w;
  const int wi = (winl >> 3) & 7;
  const int wj = winl & 7;
  const int type = ((wi == 7) ? 2 : 0) | ((wj == 7) ? 1 : 0);

  u16* wb = wbuf[w];
  const size_t wrow = (size_t)winl * 49;
  // ---- stage Q,K via gll16 (contiguous rows; pad tokens -> zpad) ----
  #pragma unroll
  for (int c = 0; c < 4; ++c) {
    int tok = c * 16 + (lane >> 2), sub = lane & 3;
    const u16 *gq, *gk;
    if (tok < 49) {
      const u16* g = QKVb + (wrow + tok) * 768 + h * 32 + sub * 8;
      gq = g; gk = g + 256;
    } else {
      gq = zpad + sub * 8; gk = zpad + sub * 8;
    }
    gll16(gq, (const char*)wb + c * 1024);
    gll16(gk, (const char*)wb + 4096 + c * 1024);
  }
  // ---- V rows (registers) ----
  short8 v0 = {}, v1 = {}, v2 = {}, v3 = {};
  {
    int tok = lane;
    if (tok < 49) {
      const short8* g = reinterpret_cast<const short8*>(
          QKVb + (wrow + tok) * 768 + 512 + h * 32);
      v0 = g[0]; v1 = g[1]; v2 = g[2]; v3 = g[3];
    }
  }
  // ---- bias fragment: 8 coalesced 16B loads/lane (issued early, overlap) ----
  const u16* bb = biasM + ((((type << 3) + h) << 12) + (quad << 8) + (l15 << 4));
  short8 bf0[4], bf1[4];
  #pragma unroll
  for (int mt = 0; mt < 4; ++mt) {
    bf0[mt] = *reinterpret_cast<const short8*>(bb + (mt << 10));
    bf1[mt] = *reinterpret_cast<const short8*>(bb + (mt << 10) + 8);
  }
  // ---- V transpose into LDS ----
  {
    int tok = lane;
    #pragma unroll
    for (int d = 0; d < 8; ++d) {
      wb[4096 + (d     ) * 64 + tok] = (u16)v0[d];
      wb[4096 + (d +  8) * 64 + tok] = (u16)v1[d];
      wb[4096 + (d + 16) * 64 + tok] = (u16)v2[d];
      wb[4096 + (d + 24) * 64 + tok] = (u16)v3[d];
    }
  }
  FENCE_VM(); FENCE_LGKM();

  // ---- scores ----
  const floatx4 z4 = {0.f, 0.f, 0.f, 0.f};
  short8 qf[4], kf[4];
  #pragma unroll
  for (int mt = 0; mt < 4; ++mt)
    qf[mt] = *reinterpret_cast<const short8*>(&wb[(16 * mt + l15) * 32 + quad * 8]);
  #pragma unroll
  for (int nt = 0; nt < 4; ++nt)
    kf[nt] = *reinterpret_cast<const short8*>(&wb[2048 + (16 * nt + l15) * 32 + quad * 8]);
  floatx4 sc[4][4];
  #pragma unroll
  for (int mt = 0; mt < 4; ++mt)
    #pragma unroll
    for (int nt = 0; nt < 4; ++nt) sc[mt][nt] = MFMA(qf[mt], kf[nt], z4);

  // ---- scale + fused bias/mask (no branches) ----
  #pragma unroll
  for (int mt = 0; mt < 4; ++mt)
    #pragma unroll
    for (int nt = 0; nt < 4; ++nt)
      #pragma unroll
      for (int reg = 0; reg < 4; ++reg) {
        u16 bv = (nt < 2) ? (u16)bf0[mt][(nt << 2) | reg]
                          : (u16)bf1[mt][((nt & 1) << 2) | reg];
        sc[mt][nt][reg] = sc[mt][nt][reg] * SCALE + bflo((u32)bv);
      }
  // ---- softmax per row ----
  #pragma unroll
  for (int mt = 0; mt < 4; ++mt)
    #pragma unroll
    for (int reg = 0; reg < 4; ++reg) {
      float m = fmaxf(fmaxf(sc[mt][0][reg], sc[mt][1][reg]),
                      fmaxf(sc[mt][2][reg], sc[mt][3][reg]));
      m = fmaxf(m, __shfl_xor(m, 1)); m = fmaxf(m, __shfl_xor(m, 2));
      m = fmaxf(m, __shfl_xor(m, 4)); m = fmaxf(m, __shfl_xor(m, 8));
      float sum = 0.f;
      #pragma unroll
      for (int nt = 0; nt < 4; ++nt) {
        float e = __expf(sc[mt][nt][reg] - m);
        sc[mt][nt][reg] = e; sum += e;
      }
      sum += __shfl_xor(sum, 1); sum += __shfl_xor(sum, 2);
      sum += __shfl_xor(sum, 4); sum += __shfl_xor(sum, 8);
      float inv = 1.f / sum;
      #pragma unroll
      for (int nt = 0; nt < 4; ++nt) sc[mt][nt][reg] *= inv;
    }
  // ---- P -> LDS (overlays Q,K) ----
  #pragma unroll
  for (int mt = 0; mt < 4; ++mt)
    #pragma unroll
    for (int nt = 0; nt < 4; ++nt)
      #pragma unroll
      for (int reg = 0; reg < 4; ++reg)
        wb[(16 * mt + 4 * quad + reg) * 64 + 16 * nt + l15] = f2bf(sc[mt][nt][reg]);
  FENCE_LGKM();
  // ---- PV ----
  floatx4 oa[4][2];
  #pragma unroll
  for (int mt = 0; mt < 4; ++mt) { oa[mt][0] = z4; oa[mt][1] = z4; }
  #pragma unroll
  for (int ks = 0; ks < 2; ++ks) {
    short8 pf[4], vf[2];
    #pragma unroll
    for (int mt = 0; mt < 4; ++mt)
      pf[mt] = *reinterpret_cast<const short8*>(
          &wb[(16 * mt + l15) * 64 + ks * 32 + quad * 8]);
    #pragma unroll
    for (int ntl = 0; ntl < 2; ++ntl)
      vf[ntl] = *reinterpret_cast<const short8*>(
          &wb[4096 + (16 * ntl + l15) * 64 + ks * 32 + quad * 8]);
    #pragma unroll
    for (int mt = 0; mt < 4; ++mt)
      #pragma unroll
      for (int ntl = 0; ntl < 2; ++ntl)
        oa[mt][ntl] = MFMA(pf[mt], vf[ntl], oa[mt][ntl]);
  }
  FENCE_LGKM();
  // ---- O transpose (overlays Vt), coalesced store ----
  #pragma unroll
  for (int mt = 0; mt < 4; ++mt)
    #pragma unroll
    for (int ntl = 0; ntl < 2; ++ntl)
      #pragma unroll
      for (int reg = 0; reg < 4; ++reg)
        wb[4096 + (16 * mt + 4 * quad + reg) * 32 + 16 * ntl + l15] =
            f2bf(oa[mt][ntl][reg]);
  FENCE_LGKM();
  #pragma unroll
  for (int c = 0; c < 4; ++c) {
    int slot = c * 64 + lane;
    if (slot < 196) {
      int tok = slot >> 2, sub = slot & 3;
      uint4 v = *reinterpret_cast<const uint4*>(&wb[4096 + tok * 32 + sub * 8]);
      *reinterpret_cast<uint4*>(O + (wrow + tok) * 256 + h * 32 + sub * 8) = v;
    }
  }
}

// ---------------- Kernel 3: proj GEMM (M=Mrows, N=256) + full-line scatter -------
__global__ __launch_bounds__(256) void proj_gemm(
    const u16* __restrict__ O, const u16* __restrict__ Wtp,
    const float* __restrict__ b_proj, float* __restrict__ out,
    int img0, int Mrows, int mtiles) {
  union LU {
    struct { u16 As[128][64]; u16 Bs[128][64]; } s;
    float Cs[64][132];   // epilogue transpose buffer (33792 B)
  };
  __shared__ LU L;
  __shared__ float bps[128];
  const int tid = threadIdx.x;
  const int wgid = xcd_swizzle(blockIdx.x, mtiles * 2);
  const int n0 = (wgid & 1) << 7;
  const int m0 = (wgid >> 1) << 7;
  const int lane = tid & 63, w = tid >> 6;
  const int l15 = lane & 15, quad = lane >> 4;
  const int mq = w & 1, nq = w >> 1;
  if (tid < 128) bps[tid] = b_proj[n0 + tid];

  const floatx4 z4 = {0.f, 0.f, 0.f, 0.f};
  floatx4 acc[4][4];
  #pragma unroll
  for (int i = 0; i < 4; ++i)
    #pragma unroll
    for (int j = 0; j < 4; ++j) acc[i][j] = z4;

  for (int ki = 0; ki < 4; ++ki) {
    const int k0 = ki * 64;
    __syncthreads();
    #pragma unroll
    for (int c = 0; c < 4; ++c) {
      int e = (w * 4 + c) * 64 + lane;
      int row = e >> 3, sp = e & 7, sub = sp ^ (row & 7);
      int gr = m0 + row; if (gr >= Mrows) gr = 0;
      gll16(O + (size_t)gr * 256 + k0 + sub * 8,
            (const char*)&L.s.As[0][0] + (w * 4 + c) * 1024);
      gll16(Wtp + (size_t)(n0 + row) * 256 + k0 + sub * 8,
            (const char*)&L.s.Bs[0][0] + (w * 4 + c) * 1024);
    }
    FENCE_VM();
    __syncthreads();
    #pragma unroll
    for (int ks = 0; ks < 2; ++ks) {
      short8 af[4], bfv[4];
      #pragma unroll
      for (int mt = 0; mt < 4; ++mt) {
        int r = 64 * mq + 16 * mt + l15;
        af[mt] = *reinterpret_cast<const short8*>(
            &L.s.As[r][((4 * ks + quad) ^ (l15 & 7)) * 8]);
      }
      #pragma unroll
      for (int nt = 0; nt < 4; ++nt) {
        int r = 64 * nq + 16 * nt + l15;
        bfv[nt] = *reinterpret_cast<const short8*>(
            &L.s.Bs[r][((4 * ks + quad) ^ (l15 & 7)) * 8]);
      }
      #pragma unroll
      for (int mt = 0; mt < 4; ++mt)
        #pragma unroll
        for (int nt = 0; nt < 4; ++nt)
          acc[mt][nt] = MFMA(af[mt], bfv[nt], acc[mt][nt]);
    }
  }
  // epilogue: two 64-row passes through LDS, full-line fp32 stores
  #pragma unroll
  for (int mh = 0; mh < 2; ++mh) {
    __syncthreads();
    if (mq == mh) {
      #pragma unroll
      for (int nt = 0; nt < 4; ++nt) {
        float bias = bps[64 * nq + 16 * nt + l15];
        #pragma unroll
        for (int mt = 0; mt < 4; ++mt)
          #pragma unroll
          for (int reg = 0; reg < 4; ++reg)
            L.Cs[16 * mt + 4 * quad + reg][64 * nq + 16 * nt + l15] =
                acc[mt][nt][reg] + bias;
      }
    }
    __syncthreads();
    int r = tid >> 2, seg = tid & 3;
    int gr = m0 + mh * 64 + r;
    if (gr < Mrows) {
      u32 winl = (u32)gr / 49u;
      int tok = gr - (int)winl * 49;
      int bL = winl >> 6, wi = (winl >> 3) & 7, wj = winl & 7;
      int pr = tok / 7, pc = tok - pr * 7;
      int y = wi * 7 + pr + 3; if (y >= IMG) y -= IMG;
      int x = wj * 7 + pc + 3; if (x >= IMG) x -= IMG;
      float* op = out + (((size_t)((img0 + bL) * 3136 + y * IMG + x)) << 8) +
                  n0 + seg * 32;
      const float* src = &L.Cs[r][seg * 32];
      #pragma unroll
      for (int i = 0; i < 8; ++i)
        reinterpret_cast<float4*>(op)[i] = reinterpret_cast<const float4*>(src)[i];
    }
  }
}

extern "C" void kernel_launch(void* const* d_in, const int* in_sizes, int n_in,
                              void* d_out, int out_size, void* d_ws, size_t ws_size,
                              hipStream_t stream) {
  const float* query      = (const float*)d_in[0];
  const float* w_qkv      = (const float*)d_in[1];
  const float* b_qkv      = (const float*)d_in[2];
  const float* w_proj     = (const float*)d_in[3];
  const float* b_proj     = (const float*)d_in[4];
  const float* bias_table = (const float*)d_in[5];

  u16* wsu   = (u16*)d_ws;
  u16* zpad  = wsu;                 // 128
  u16* Wtq   = wsu + 128;           // 196608
  u16* Wtp   = wsu + 196736;        // 65536
  u16* biasM = wsu + 262272;        // 131072

  int P = 16;  // images per pass; shrink until buffers fit ws
  while (P > 1 && 2ull * (393344ull + (u64)P * 3211264ull) > (u64)ws_size) P >>= 1;
  u16* QKVb = wsu + 393344;                    // P*2408448
  u16* Ob   = QKVb + (size_t)P * 2408448;      // P*802816
  const int npass  = 16 / P;
  const int Mrows  = P * 3136;
  const int mtiles = (Mrows + 127) / 128;

  convert_kernel<<<1537, 256, 0, stream>>>(w_qkv, w_proj, bias_table,
                                           zpad, Wtq, Wtp, biasM);
  for (int p = 0; p < npass; ++p) {
    qkv_gemm<<<mtiles * 6, 256, 0, stream>>>(query, Wtq, b_qkv, QKVb,
                                             p * P, Mrows, mtiles);
    attn_kernel<<<P * 128, 256, 0, stream>>>(QKVb, biasM, zpad, Ob);
    proj_gemm<<<mtiles * 2, 256, 0, stream>>>(Ob, Wtp, b_proj, (float*)d_out,
                                              p * P, Mrows, mtiles);
  }
}

// Round 3
// 223.928 us; speedup vs baseline: 1.0282x; 1.0282x over previous
//
#include <hip/hip_runtime.h>

// Shifted-window MSA, fixed shape: B=16, H=W=56, C=256, NH=8, hd=32, WS=7, SS=3.
// Pipeline:
//   convert : weights -> transposed bf16 Wt[n][k]; zpad; biasM[type][h] =
//             (rel-pos bias + shift mask + col-pad mask) in MFMA C-fragment layout
//   qkv_gemm: QKVb[m][768] = roll/window-partition(query) @ w_qkv + b
//             (A fused: fp32 gather software-prefetched one K-tile ahead,
//              v_cvt_pk_bf16_f32 convert, ds_write; B via gll16; XCD swizzle)
//   attn    : barrier-free; 1 wave = 1 (window, head); coalesced fragment bias
//   proj    : out = O @ w_proj + b; LDS-transposed epilogue, full-line stores
// ws (u16): zpad[128]|Wtq[196608]|Wtp[65536]|biasM[131072]|
//           QKVb[P*2408448]|O[P*802816];  P = images/pass from ws_size.

#define IMG 56
#define SCALE 0.17677669529663687f

typedef unsigned short u16;
typedef unsigned int u32;
typedef unsigned long long u64;
typedef __attribute__((ext_vector_type(8))) short short8;   // 8 bf16
typedef __attribute__((ext_vector_type(4))) float floatx4;  // MFMA C/D

__device__ __forceinline__ float bflo(u32 u) { return __uint_as_float(u << 16); }
__device__ __forceinline__ u16 f2bf(float f) {
  u32 u = __float_as_uint(f);
  return (u16)((u + 0x7fffu + ((u >> 16) & 1u)) >> 16);  // RNE
}
// HW packed convert (RNE, bit-identical to f2bf): 2 floats -> 1 dword of 2 bf16.
__device__ __forceinline__ u32 cvt2(float lo, float hi) {
  u32 r;
  __asm__("v_cvt_pk_bf16_f32 %0, %1, %2" : "=v"(r) : "v"(lo), "v"(hi));
  return r;
}
__device__ __forceinline__ short8 pack8(float4 lo, float4 hi) {
  union { u32 u[4]; short8 s; } r;
  r.u[0] = cvt2(lo.x, lo.y); r.u[1] = cvt2(lo.z, lo.w);
  r.u[2] = cvt2(hi.x, hi.y); r.u[3] = cvt2(hi.z, hi.w);
  return r.s;
}
#define MFMA(a, b, c) __builtin_amdgcn_mfma_f32_16x16x32_bf16(a, b, c, 0, 0, 0)

__device__ __forceinline__ void gll16(const void* g, const void* l) {
  __builtin_amdgcn_global_load_lds(
      (const __attribute__((address_space(1))) void*)g,
      (__attribute__((address_space(3))) void*)l, 16, 0, 0);
}
#define FENCE_VM() __asm__ volatile("s_waitcnt vmcnt(0)" ::: "memory")
#define FENCE_LGKM() __asm__ volatile("s_waitcnt lgkmcnt(0)" ::: "memory")

// Bijective XCD swizzle (m204): HW sends block b to XCD b%8; give each XCD a
// contiguous chunk of the logical tile space so A-sharing blocks hit one L2.
__device__ __forceinline__ int xcd_swizzle(int orig, int nwg) {
  int q = nwg >> 3, r = nwg & 7;
  int xcd = orig & 7, loc = orig >> 3;
  return (xcd < r ? xcd * (q + 1) : r * (q + 1) + (xcd - r) * q) + loc;
}

// ---------------- Kernel 0: weights + zpad + fragment-layout bias tables --------
// biasM[type][h][mt][quad][l15][nt][reg] (bf16), type = bndH*2+bndV.
__global__ __launch_bounds__(256) void convert_kernel(
    const float* __restrict__ w_qkv, const float* __restrict__ w_proj,
    const float* __restrict__ bias_table, u16* __restrict__ zpad,
    u16* __restrict__ Wtq, u16* __restrict__ Wtp, u16* __restrict__ biasM) {
  int t = blockIdx.x * 256 + threadIdx.x;
  if (t < 196608) {            // w_qkv[k][n]
    int n = t % 768, k = t / 768;
    Wtq[n * 256 + k] = f2bf(w_qkv[t]);
  } else if (t < 262144) {     // w_proj[k][n]
    int u = t - 196608;
    int n = u & 255, k = u >> 8;
    Wtp[n * 256 + k] = f2bf(w_proj[u]);
  } else if (t < 262272) {
    zpad[t - 262144] = 0;
  } else if (t < 393344) {
    int idx = t - 262272;              // [type:2][h:3][mt:2][quad:2][l15:4][nt:2][reg:2]
    int type = idx >> 15;
    int r = idx & 32767;
    int h = r >> 12, mt = (r >> 10) & 3, quad = (r >> 8) & 3;
    int l15 = (r >> 4) & 15, nt = (r >> 2) & 3, reg = r & 3;
    int row = 16 * mt + 4 * quad + reg;
    int col = 16 * nt + l15;
    float v;
    if (col >= 49) v = -1e30f;
    else if (row >= 49) v = 0.f;
    else {
      int yn = row / 7, xn = row - yn * 7;
      int ym = col / 7, xm = col - ym * 7;
      v = bias_table[((yn - ym + 6) * 13 + (xn - xm + 6)) * 8 + h];
      int bndH = (type >> 1) & 1, bndV = type & 1;
      int rc = (bndH ? ((yn < 4) ? 1 : 2) : 0) * 3 + (bndV ? ((xn < 4) ? 1 : 2) : 0);
      int cc = (bndH ? ((ym < 4) ? 1 : 2) : 0) * 3 + (bndV ? ((xm < 4) ? 1 : 2) : 0);
      if (rc != cc) v -= 100.f;
    }
    biasM[idx] = f2bf(v);
  }
}

// ---------------- Kernel 1: QKV GEMM (M=Mrows, N=768, K=256), fused xconv -------
// A rows come straight from query (fp32) with the roll/window-partition mapping;
// loads for tile ki+1 are issued during tile ki's MFMA phase (latency hidden),
// converted with v_cvt_pk_bf16_f32 and ds_written into the swizzled LDS slot.
__global__ __launch_bounds__(256) void qkv_gemm(
    const float* __restrict__ query, const u16* __restrict__ Wtq,
    const float* __restrict__ b_qkv, u16* __restrict__ QKVb,
    int img0, int Mrows, int mtiles) {
  union LU {
    struct { u16 As[128][64]; u16 Bs[128][64]; } s;
    u16 Cs[128][144];
  };
  __shared__ LU L;
  __shared__ float bqs[128];
  const int tid = threadIdx.x;
  const int wgid = xcd_swizzle(blockIdx.x, mtiles * 6);
  const int n0 = (wgid % 6) << 7;   // n-inner: 6 consecutive logical blocks share A
  const int m0 = (wgid / 6) << 7;
  const int lane = tid & 63, w = tid >> 6;
  const int l15 = lane & 15, quad = lane >> 4;
  const int mq = w & 1, nq = w >> 1;
  if (tid < 128) bqs[tid] = b_qkv[n0 + tid];

  // Per-c staging geometry (ki-invariant): query base for the A row's
  // (rolled, window-partitioned) token, and the matching Wtq base.
  const float* qsrc[4];
  const u16* wsrc[4];
  #pragma unroll
  for (int c = 0; c < 4; ++c) {
    int e = (w * 4 + c) * 64 + lane;         // 0..1023
    int row = e >> 3, sp = e & 7, sub = sp ^ (row & 7);
    int gr = m0 + row; if (gr >= Mrows) gr = 0;
    int winl = gr / 49, tok = gr - winl * 49;
    int bL = winl >> 6, wi = (winl >> 3) & 7, wj = winl & 7;
    int pr = tok / 7, pc = tok - pr * 7;
    int y = wi * 7 + pr + 3; if (y >= IMG) y -= IMG;
    int x = wj * 7 + pc + 3; if (x >= IMG) x -= IMG;
    qsrc[c] = query + (((size_t)((img0 + bL) * 3136 + y * IMG + x)) << 8) + sub * 8;
    wsrc[c] = Wtq + (size_t)(n0 + row) * 256 + sub * 8;
  }

  const floatx4 z4 = {0.f, 0.f, 0.f, 0.f};
  floatx4 acc[4][4];
  #pragma unroll
  for (int i = 0; i < 4; ++i)
    #pragma unroll
    for (int j = 0; j < 4; ++j) acc[i][j] = z4;

  // prologue: issue A loads for ki=0
  float4 a0[4], a1[4];
  #pragma unroll
  for (int c = 0; c < 4; ++c) {
    a0[c] = reinterpret_cast<const float4*>(qsrc[c])[0];
    a1[c] = reinterpret_cast<const float4*>(qsrc[c])[1];
  }

  for (int ki = 0; ki < 4; ++ki) {
    const int k0 = ki * 64;
    __syncthreads();
    // B: gll16 issued first — flies under the A convert VALU work
    #pragma unroll
    for (int c = 0; c < 4; ++c)
      gll16(wsrc[c] + k0, (const char*)&L.s.Bs[0][0] + (w * 4 + c) * 1024);
    // A: hw pack-convert the prefetched regs, vector ds_write
    #pragma unroll
    for (int c = 0; c < 4; ++c) {
      short8 pk = pack8(a0[c], a1[c]);
      *reinterpret_cast<short8*>(
          (char*)&L.s.As[0][0] + (w * 4 + c) * 1024 + lane * 16) = pk;
    }
    FENCE_VM();
    __syncthreads();   // barrier drains lgkm -> ds_writes visible
    // prefetch A for ki+1: in flight across the whole MFMA phase
    {
      const int kn = (ki < 3) ? k0 + 64 : 0;   // clamp keeps addr in-bounds
      #pragma unroll
      for (int c = 0; c < 4; ++c) {
        const float* src = qsrc[c] + kn;
        a0[c] = reinterpret_cast<const float4*>(src)[0];
        a1[c] = reinterpret_cast<const float4*>(src)[1];
      }
    }
    #pragma unroll
    for (int ks = 0; ks < 2; ++ks) {
      short8 af[4], bfv[4];
      #pragma unroll
      for (int mt = 0; mt < 4; ++mt) {
        int r = 64 * mq + 16 * mt + l15;
        af[mt] = *reinterpret_cast<const short8*>(
            &L.s.As[r][((4 * ks + quad) ^ (l15 & 7)) * 8]);
      }
      #pragma unroll
      for (int nt = 0; nt < 4; ++nt) {
        int r = 64 * nq + 16 * nt + l15;
        bfv[nt] = *reinterpret_cast<const short8*>(
            &L.s.Bs[r][((4 * ks + quad) ^ (l15 & 7)) * 8]);
      }
      #pragma unroll
      for (int mt = 0; mt < 4; ++mt)
        #pragma unroll
        for (int nt = 0; nt < 4; ++nt)
          acc[mt][nt] = MFMA(af[mt], bfv[nt], acc[mt][nt]);
    }
  }
  __syncthreads();
  #pragma unroll
  for (int mt = 0; mt < 4; ++mt)
    #pragma unroll
    for (int nt = 0; nt < 4; ++nt) {
      float bias = bqs[64 * nq + 16 * nt + l15];
      #pragma unroll
      for (int reg = 0; reg < 4; ++reg) {
        int row = 64 * mq + 16 * mt + 4 * quad + reg;
        int col = 64 * nq + 16 * nt + l15;
        L.Cs[row][col] = f2bf(acc[mt][nt][reg] + bias);
      }
    }
  __syncthreads();
  int r = tid >> 1, half = tid & 1;
  if (m0 + r < Mrows) {
    u16* dst = QKVb + (size_t)(m0 + r) * 768 + n0 + half * 64;
    const u16* src = &L.Cs[r][half * 64];
    #pragma unroll
    for (int it = 0; it < 8; ++it)
      reinterpret_cast<uint4*>(dst)[it] = reinterpret_cast<const uint4*>(src)[it];
  }
}

// ---------------- Kernel 2: attention — barrier-free, 1 wave = (window, head) ----
__global__ __launch_bounds__(256) void attn_kernel(
    const u16* __restrict__ QKVb, const u16* __restrict__ biasM,
    const u16* __restrict__ zpad, u16* __restrict__ O) {
  __shared__ __align__(16) u16 wbuf[4][6144];  // per-wave: Q[64][32],K[64][32],Vt[32][64]
  const int tid = threadIdx.x;
  const int winl = blockIdx.x >> 1;
  const int hg = (blockIdx.x & 1) * 4;
  const int lane = tid & 63, w = tid >> 6;
  const int l15 = lane & 15, quad = lane >> 4;
  const int h = hg + w;
  const int wi = (winl >> 3) & 7;
  const int wj = winl & 7;
  const int type = ((wi == 7) ? 2 : 0) | ((wj == 7) ? 1 : 0);

  u16* wb = wbuf[w];
  const size_t wrow = (size_t)winl * 49;
  // ---- stage Q,K via gll16 (contiguous rows; pad tokens -> zpad) ----
  #pragma unroll
  for (int c = 0; c < 4; ++c) {
    int tok = c * 16 + (lane >> 2), sub = lane & 3;
    const u16 *gq, *gk;
    if (tok < 49) {
      const u16* g = QKVb + (wrow + tok) * 768 + h * 32 + sub * 8;
      gq = g; gk = g + 256;
    } else {
      gq = zpad + sub * 8; gk = zpad + sub * 8;
    }
    gll16(gq, (const char*)wb + c * 1024);
    gll16(gk, (const char*)wb + 4096 + c * 1024);
  }
  // ---- V rows (registers) ----
  short8 v0 = {}, v1 = {}, v2 = {}, v3 = {};
  {
    int tok = lane;
    if (tok < 49) {
      const short8* g = reinterpret_cast<const short8*>(
          QKVb + (wrow + tok) * 768 + 512 + h * 32);
      v0 = g[0]; v1 = g[1]; v2 = g[2]; v3 = g[3];
    }
  }
  // ---- bias fragment: 8 coalesced 16B loads/lane (issued early, overlap) ----
  const u16* bb = biasM + ((((type << 3) + h) << 12) + (quad << 8) + (l15 << 4));
  short8 bf0[4], bf1[4];
  #pragma unroll
  for (int mt = 0; mt < 4; ++mt) {
    bf0[mt] = *reinterpret_cast<const short8*>(bb + (mt << 10));
    bf1[mt] = *reinterpret_cast<const short8*>(bb + (mt << 10) + 8);
  }
  // ---- V transpose into LDS ----
  {
    int tok = lane;
    #pragma unroll
    for (int d = 0; d < 8; ++d) {
      wb[4096 + (d     ) * 64 + tok] = (u16)v0[d];
      wb[4096 + (d +  8) * 64 + tok] = (u16)v1[d];
      wb[4096 + (d + 16) * 64 + tok] = (u16)v2[d];
      wb[4096 + (d + 24) * 64 + tok] = (u16)v3[d];
    }
  }
  FENCE_VM(); FENCE_LGKM();

  // ---- scores ----
  const floatx4 z4 = {0.f, 0.f, 0.f, 0.f};
  short8 qf[4], kf[4];
  #pragma unroll
  for (int mt = 0; mt < 4; ++mt)
    qf[mt] = *reinterpret_cast<const short8*>(&wb[(16 * mt + l15) * 32 + quad * 8]);
  #pragma unroll
  for (int nt = 0; nt < 4; ++nt)
    kf[nt] = *reinterpret_cast<const short8*>(&wb[2048 + (16 * nt + l15) * 32 + quad * 8]);
  floatx4 sc[4][4];
  #pragma unroll
  for (int mt = 0; mt < 4; ++mt)
    #pragma unroll
    for (int nt = 0; nt < 4; ++nt) sc[mt][nt] = MFMA(qf[mt], kf[nt], z4);

  // ---- scale + fused bias/mask (no branches) ----
  #pragma unroll
  for (int mt = 0; mt < 4; ++mt)
    #pragma unroll
    for (int nt = 0; nt < 4; ++nt)
      #pragma unroll
      for (int reg = 0; reg < 4; ++reg) {
        u16 bv = (nt < 2) ? (u16)bf0[mt][(nt << 2) | reg]
                          : (u16)bf1[mt][((nt & 1) << 2) | reg];
        sc[mt][nt][reg] = sc[mt][nt][reg] * SCALE + bflo((u32)bv);
      }
  // ---- softmax per row ----
  #pragma unroll
  for (int mt = 0; mt < 4; ++mt)
    #pragma unroll
    for (int reg = 0; reg < 4; ++reg) {
      float m = fmaxf(fmaxf(sc[mt][0][reg], sc[mt][1][reg]),
                      fmaxf(sc[mt][2][reg], sc[mt][3][reg]));
      m = fmaxf(m, __shfl_xor(m, 1)); m = fmaxf(m, __shfl_xor(m, 2));
      m = fmaxf(m, __shfl_xor(m, 4)); m = fmaxf(m, __shfl_xor(m, 8));
      float sum = 0.f;
      #pragma unroll
      for (int nt = 0; nt < 4; ++nt) {
        float e = __expf(sc[mt][nt][reg] - m);
        sc[mt][nt][reg] = e; sum += e;
      }
      sum += __shfl_xor(sum, 1); sum += __shfl_xor(sum, 2);
      sum += __shfl_xor(sum, 4); sum += __shfl_xor(sum, 8);
      float inv = 1.f / sum;
      #pragma unroll
      for (int nt = 0; nt < 4; ++nt) sc[mt][nt][reg] *= inv;
    }
  // ---- P -> LDS (overlays Q,K) ----
  #pragma unroll
  for (int mt = 0; mt < 4; ++mt)
    #pragma unroll
    for (int nt = 0; nt < 4; ++nt)
      #pragma unroll
      for (int reg = 0; reg < 4; ++reg)
        wb[(16 * mt + 4 * quad + reg) * 64 + 16 * nt + l15] = f2bf(sc[mt][nt][reg]);
  FENCE_LGKM();
  // ---- PV ----
  floatx4 oa[4][2];
  #pragma unroll
  for (int mt = 0; mt < 4; ++mt) { oa[mt][0] = z4; oa[mt][1] = z4; }
  #pragma unroll
  for (int ks = 0; ks < 2; ++ks) {
    short8 pf[4], vf[2];
    #pragma unroll
    for (int mt = 0; mt < 4; ++mt)
      pf[mt] = *reinterpret_cast<const short8*>(
          &wb[(16 * mt + l15) * 64 + ks * 32 + quad * 8]);
    #pragma unroll
    for (int ntl = 0; ntl < 2; ++ntl)
      vf[ntl] = *reinterpret_cast<const short8*>(
          &wb[4096 + (16 * ntl + l15) * 64 + ks * 32 + quad * 8]);
    #pragma unroll
    for (int mt = 0; mt < 4; ++mt)
      #pragma unroll
      for (int ntl = 0; ntl < 2; ++ntl)
        oa[mt][ntl] = MFMA(pf[mt], vf[ntl], oa[mt][ntl]);
  }
  FENCE_LGKM();
  // ---- O transpose (overlays Vt), coalesced store ----
  #pragma unroll
  for (int mt = 0; mt < 4; ++mt)
    #pragma unroll
    for (int ntl = 0; ntl < 2; ++ntl)
      #pragma unroll
      for (int reg = 0; reg < 4; ++reg)
        wb[4096 + (16 * mt + 4 * quad + reg) * 32 + 16 * ntl + l15] =
            f2bf(oa[mt][ntl][reg]);
  FENCE_LGKM();
  #pragma unroll
  for (int c = 0; c < 4; ++c) {
    int slot = c * 64 + lane;
    if (slot < 196) {
      int tok = slot >> 2, sub = slot & 3;
      uint4 v = *reinterpret_cast<const uint4*>(&wb[4096 + tok * 32 + sub * 8]);
      *reinterpret_cast<uint4*>(O + (wrow + tok) * 256 + h * 32 + sub * 8) = v;
    }
  }
}

// ---------------- Kernel 3: proj GEMM (M=Mrows, N=256) + full-line scatter -------
__global__ __launch_bounds__(256) void proj_gemm(
    const u16* __restrict__ O, const u16* __restrict__ Wtp,
    const float* __restrict__ b_proj, float* __restrict__ out,
    int img0, int Mrows, int mtiles) {
  union LU {
    struct { u16 As[128][64]; u16 Bs[128][64]; } s;
    float Cs[64][132];   // epilogue transpose buffer (33792 B)
  };
  __shared__ LU L;
  __shared__ float bps[128];
  const int tid = threadIdx.x;
  const int wgid = xcd_swizzle(blockIdx.x, mtiles * 2);
  const int n0 = (wgid & 1) << 7;
  const int m0 = (wgid >> 1) << 7;
  const int lane = tid & 63, w = tid >> 6;
  const int l15 = lane & 15, quad = lane >> 4;
  const int mq = w & 1, nq = w >> 1;
  if (tid < 128) bps[tid] = b_proj[n0 + tid];

  const floatx4 z4 = {0.f, 0.f, 0.f, 0.f};
  floatx4 acc[4][4];
  #pragma unroll
  for (int i = 0; i < 4; ++i)
    #pragma unroll
    for (int j = 0; j < 4; ++j) acc[i][j] = z4;

  for (int ki = 0; ki < 4; ++ki) {
    const int k0 = ki * 64;
    __syncthreads();
    #pragma unroll
    for (int c = 0; c < 4; ++c) {
      int e = (w * 4 + c) * 64 + lane;
      int row = e >> 3, sp = e & 7, sub = sp ^ (row & 7);
      int gr = m0 + row; if (gr >= Mrows) gr = 0;
      gll16(O + (size_t)gr * 256 + k0 + sub * 8,
            (const char*)&L.s.As[0][0] + (w * 4 + c) * 1024);
      gll16(Wtp + (size_t)(n0 + row) * 256 + k0 + sub * 8,
            (const char*)&L.s.Bs[0][0] + (w * 4 + c) * 1024);
    }
    FENCE_VM();
    __syncthreads();
    #pragma unroll
    for (int ks = 0; ks < 2; ++ks) {
      short8 af[4], bfv[4];
      #pragma unroll
      for (int mt = 0; mt < 4; ++mt) {
        int r = 64 * mq + 16 * mt + l15;
        af[mt] = *reinterpret_cast<const short8*>(
            &L.s.As[r][((4 * ks + quad) ^ (l15 & 7)) * 8]);
      }
      #pragma unroll
      for (int nt = 0; nt < 4; ++nt) {
        int r = 64 * nq + 16 * nt + l15;
        bfv[nt] = *reinterpret_cast<const short8*>(
            &L.s.Bs[r][((4 * ks + quad) ^ (l15 & 7)) * 8]);
      }
      #pragma unroll
      for (int mt = 0; mt < 4; ++mt)
        #pragma unroll
        for (int nt = 0; nt < 4; ++nt)
          acc[mt][nt] = MFMA(af[mt], bfv[nt], acc[mt][nt]);
    }
  }
  // epilogue: two 64-row passes through LDS, full-line fp32 stores
  #pragma unroll
  for (int mh = 0; mh < 2; ++mh) {
    __syncthreads();
    if (mq == mh) {
      #pragma unroll
      for (int nt = 0; nt < 4; ++nt) {
        float bias = bps[64 * nq + 16 * nt + l15];
        #pragma unroll
        for (int mt = 0; mt < 4; ++mt)
          #pragma unroll
          for (int reg = 0; reg < 4; ++reg)
            L.Cs[16 * mt + 4 * quad + reg][64 * nq + 16 * nt + l15] =
                acc[mt][nt][reg] + bias;
      }
    }
    __syncthreads();
    int r = tid >> 2, seg = tid & 3;
    int gr = m0 + mh * 64 + r;
    if (gr < Mrows) {
      u32 winl = (u32)gr / 49u;
      int tok = gr - (int)winl * 49;
      int bL = winl >> 6, wi = (winl >> 3) & 7, wj = winl & 7;
      int pr = tok / 7, pc = tok - pr * 7;
      int y = wi * 7 + pr + 3; if (y >= IMG) y -= IMG;
      int x = wj * 7 + pc + 3; if (x >= IMG) x -= IMG;
      float* op = out + (((size_t)((img0 + bL) * 3136 + y * IMG + x)) << 8) +
                  n0 + seg * 32;
      const float* src = &L.Cs[r][seg * 32];
      #pragma unroll
      for (int i = 0; i < 8; ++i)
        reinterpret_cast<float4*>(op)[i] = reinterpret_cast<const float4*>(src)[i];
    }
  }
}

extern "C" void kernel_launch(void* const* d_in, const int* in_sizes, int n_in,
                              void* d_out, int out_size, void* d_ws, size_t ws_size,
                              hipStream_t stream) {
  const float* query      = (const float*)d_in[0];
  const float* w_qkv      = (const float*)d_in[1];
  const float* b_qkv      = (const float*)d_in[2];
  const float* w_proj     = (const float*)d_in[3];
  const float* b_proj     = (const float*)d_in[4];
  const float* bias_table = (const float*)d_in[5];

  u16* wsu   = (u16*)d_ws;
  u16* zpad  = wsu;                 // 128
  u16* Wtq   = wsu + 128;           // 196608
  u16* Wtp   = wsu + 196736;        // 65536
  u16* biasM = wsu + 262272;        // 131072

  int P = 16;  // images per pass; shrink until buffers fit ws
  while (P > 1 && 2ull * (393344ull + (u64)P * 3211264ull) > (u64)ws_size) P >>= 1;
  u16* QKVb = wsu + 393344;                    // P*2408448
  u16* Ob   = QKVb + (size_t)P * 2408448;      // P*802816
  const int npass  = 16 / P;
  const int Mrows  = P * 3136;
  const int mtiles = (Mrows + 127) / 128;

  convert_kernel<<<1537, 256, 0, stream>>>(w_qkv, w_proj, bias_table,
                                           zpad, Wtq, Wtp, biasM);
  for (int p = 0; p < npass; ++p) {
    qkv_gemm<<<mtiles * 6, 256, 0, stream>>>(query, Wtq, b_qkv, QKVb,
                                             p * P, Mrows, mtiles);
    attn_kernel<<<P * 128, 256, 0, stream>>>(QKVb, biasM, zpad, Ob);
    proj_gemm<<<mtiles * 2, 256, 0, stream>>>(Ob, Wtp, b_proj, (float*)d_out,
                                              p * P, Mrows, mtiles);
  }
}